// Round 8
// baseline (220.268 us; speedup 1.0000x reference)
//
#include <hip/hip_runtime.h>
#include <hip/hip_bf16.h>

typedef unsigned short u16;
typedef unsigned int u32;
typedef __bf16 bf16x8 __attribute__((ext_vector_type(8)));
typedef float f32x4 __attribute__((ext_vector_type(4)));

__device__ __forceinline__ float bfu(u16 u) { return __uint_as_float(((u32)u) << 16); }
__device__ __forceinline__ u16 fbf(float f) {
  __hip_bfloat16 h = __float2bfloat16(f);
  return *reinterpret_cast<u16*>(&h);
}
__device__ __forceinline__ float softplusf(float z) {
  float t = __expf(z);
  return (z > 20.f) ? z : __logf(1.f + t);
}
__device__ __forceinline__ float lo16(u32 p) { return __uint_as_float(p << 16); }
__device__ __forceinline__ float hi16(u32 p) { return __uint_as_float(p & 0xffff0000u); }
__device__ __forceinline__ bf16x8 ld_bf8(const u16* p) {
  union { uint4 u; bf16x8 v; } c;
  c.u = *(const uint4*)p;
  return c.v;
}

// xc layout is GROUP-BLOCKED channels-last: [b][g][y][x][c16] (u16 units:
// base + ((b*8+g)<<18) + ((y*128+x)<<4) + c).

// ---- K1: in_proj MFMA GEMM + (block 1024) k_sums fold ----------------------
__global__ __launch_bounds__(256) void k_inproj(const float* __restrict__ X,
                                                const float* __restrict__ W,
                                                u16* __restrict__ out,
                                                const float* __restrict__ W2,
                                                const float* __restrict__ gO,
                                                const float* __restrict__ bO,
                                                float* __restrict__ s12) {
  __shared__ __align__(16) u16 Ws[128 * 136];  // [o][c] bf16
  __shared__ __align__(16) u16 Xs[64 * 136];   // [l][c] bf16 (X^T tile)
  int tid = threadIdx.x;
  if (blockIdx.x == 1024) {  // folded k_sums
    if (tid < 128) {
      int o = tid;
      float s1 = 0.f, s2 = 0.f;
      for (int c = 0; c < 128; ++c) {
        float w = W2[(o << 7) + c];
        s1 = fmaf(w, bO[c], s1);
        s2 = fmaf(w, gO[c], s2);
      }
      s12[o] = s1;
      s12[128 + o] = s2;
    }
    return;
  }
  int b = blockIdx.x >> 8;
  int l0 = (blockIdx.x & 255) << 6;
  for (int i = 0; i < 16; ++i) {
    int idx = (i << 8) + tid;
    int o = idx >> 5, c4 = (idx & 31) << 2;
    float4 w4 = *(const float4*)&W[(o << 7) + c4];
    ushort4 s;
    s.x = fbf(w4.x); s.y = fbf(w4.y); s.z = fbf(w4.z); s.w = fbf(w4.w);
    *(ushort4*)&Ws[o * 136 + c4] = s;
  }
  for (int i = 0; i < 8; ++i) {
    int idx = (i << 8) + tid;
    int c = idx >> 4, lq = (idx & 15) << 2;
    float4 x4 = *(const float4*)&X[(((long)(b << 7) + c) << 14) + l0 + lq];
    Xs[(lq + 0) * 136 + c] = fbf(x4.x);
    Xs[(lq + 1) * 136 + c] = fbf(x4.y);
    Xs[(lq + 2) * 136 + c] = fbf(x4.z);
    Xs[(lq + 3) * 136 + c] = fbf(x4.w);
  }
  __syncthreads();
  int w = tid >> 6, lane = tid & 63;
  int mrow = lane & 15, quad = lane >> 4;
  f32x4 acc[2][4];
#pragma unroll
  for (int ot = 0; ot < 2; ++ot)
#pragma unroll
    for (int lt = 0; lt < 4; ++lt) acc[ot][lt] = (f32x4){0.f, 0.f, 0.f, 0.f};
#pragma unroll
  for (int kb = 0; kb < 4; ++kb) {
    int c0 = (kb << 5) + (quad << 3);
    bf16x8 af[2], bfr[4];
#pragma unroll
    for (int ot = 0; ot < 2; ++ot)
      af[ot] = ld_bf8(&Ws[((w << 5) + (ot << 4) + mrow) * 136 + c0]);
#pragma unroll
    for (int lt = 0; lt < 4; ++lt)
      bfr[lt] = ld_bf8(&Xs[((lt << 4) + mrow) * 136 + c0]);
#pragma unroll
    for (int ot = 0; ot < 2; ++ot)
#pragma unroll
      for (int lt = 0; lt < 4; ++lt)
        acc[ot][lt] = __builtin_amdgcn_mfma_f32_16x16x32_bf16(af[ot], bfr[lt], acc[ot][lt], 0, 0, 0);
  }
#pragma unroll
  for (int ot = 0; ot < 2; ++ot)
#pragma unroll
    for (int lt = 0; lt < 4; ++lt) {
      int l = l0 + (lt << 4) + mrow;
      int o = (w << 5) + (ot << 4) + (quad << 2);
      ushort4 s;
      s.x = fbf(acc[ot][lt][0]); s.y = fbf(acc[ot][lt][1]);
      s.z = fbf(acc[ot][lt][2]); s.w = fbf(acc[ot][lt][3]);
      *(ushort4*)&out[(((long)(b << 14) + l) << 7) + o] = s;
    }
}

// ---- K2: depthwise 3x3 conv + SiLU; in [l][c128], out group-blocked --------
__global__ __launch_bounds__(256) void k_dwconv(const u16* __restrict__ in,
                                                const float* __restrict__ w9,
                                                const float* __restrict__ bias,
                                                u16* __restrict__ out) {
  __shared__ float wsT[9][128];
  __shared__ float bs[128];
  int tid = threadIdx.x;
  for (int i = 0; i < 5; ++i) {
    int lin = (i << 8) + tid;
    if (lin < 1152) { int c = lin / 9, k = lin - 9 * c; wsT[k][c] = w9[lin]; }
  }
  if (tid < 128) bs[tid] = bias[tid];
  __syncthreads();
  int blk = blockIdx.x;
  int b = blk >> 10;
  int s = blk & 1023;
  int h = s >> 3;
  int w = ((s & 7) << 4) + (tid >> 4);
  int c0 = (tid & 15) << 3;
  const u16* bbase = in + ((long)b << 21);
  float acc[8];
  {
    float4 b0 = *(const float4*)&bs[c0];
    float4 b1 = *(const float4*)&bs[c0 + 4];
    acc[0] = b0.x; acc[1] = b0.y; acc[2] = b0.z; acc[3] = b0.w;
    acc[4] = b1.x; acc[5] = b1.y; acc[6] = b1.z; acc[7] = b1.w;
  }
#pragma unroll
  for (int ky = -1; ky <= 1; ++ky) {
    int y = h + ky;
    if ((unsigned)y >= 128u) continue;
#pragma unroll
    for (int kx = -1; kx <= 1; ++kx) {
      int x = w + kx;
      if ((unsigned)x >= 128u) continue;
      int k = (ky + 1) * 3 + (kx + 1);
      uint4 v = *(const uint4*)(bbase + ((((y << 7) + x)) << 7) + c0);
      float4 w0 = *(const float4*)&wsT[k][c0];
      float4 w1 = *(const float4*)&wsT[k][c0 + 4];
      u32 vv[4] = {v.x, v.y, v.z, v.w};
      float wf[8] = {w0.x, w0.y, w0.z, w0.w, w1.x, w1.y, w1.z, w1.w};
#pragma unroll
      for (int cc = 0; cc < 8; ++cc) {
        float xv = (cc & 1) ? hi16(vv[cc >> 1]) : lo16(vv[cc >> 1]);
        acc[cc] = fmaf(wf[cc], xv, acc[cc]);
      }
    }
  }
#pragma unroll
  for (int cc = 0; cc < 8; ++cc) acc[cc] = acc[cc] / (1.f + __expf(-acc[cc]));
  int g4 = c0 >> 4, sub = c0 & 15;
  uint4 pkst;
  pkst.x = (u32)fbf(acc[0]) | ((u32)fbf(acc[1]) << 16);
  pkst.y = (u32)fbf(acc[2]) | ((u32)fbf(acc[3]) << 16);
  pkst.z = (u32)fbf(acc[4]) | ((u32)fbf(acc[5]) << 16);
  pkst.w = (u32)fbf(acc[6]) | ((u32)fbf(acc[7]) << 16);
  u16* po = out + (((long)(b << 3) + g4) << 18) + ((((h << 7) + w)) << 4) + sub;
  *(uint4*)po = pkst;
}

// ---- K3: FUSED dwconv#2 + LN + GELU + offset MFMA + DCN gather + x_proj ----
// v8: LDS squeezed under 40KB -> 4 blocks/CU (32 waves, HW max; was 3/24).
// r7 showed the kernel is latency-bound (conflict fix matched its counter
// prediction but not the time): phases serialize behind barriers and 3
// resident blocks can't cover the stalls.  Overlay plan (single 37632B
// union):
//   Phase A/B live: Ge[0,17408) | wpad[17408,22144) | Wos[22144,26496)
//   Phase B writes offsL[17408,21504) (wpad dead after A)
//   Phase C live:   part[0,20736)  | xds_bf[20736,37632) (Ge/Wos dead)
// A barrier right after the offsL read orders it against part/xds_bf
// overwrites.  bias/gamma/beta LDS staging dropped (global reads, L1-hot).
// xdblT (2KB) stays separate.  Total ~39.7KB.
__global__ __launch_bounds__(512, 8) void k_dcnoff(const u16* __restrict__ xc,
                                                   const float* __restrict__ w9,
                                                   const float* __restrict__ bias,
                                                   const float* __restrict__ g,
                                                   const float* __restrict__ bt,
                                                   const float* __restrict__ offw,
                                                   const float* __restrict__ offb,
                                                   const float* __restrict__ xpw,
                                                   const float* __restrict__ dtw,
                                                   u16* __restrict__ xs,
                                                   u16* __restrict__ dts,
                                                   float* __restrict__ Bsb,
                                                   float* __restrict__ Csb) {
  __shared__ __align__(16) char uni[37632];
  __shared__ __align__(16) float xdblT[8 * 64];   // [r][p]
  u16* Ge = (u16*)uni;                     // [0,17408)   Phase A write / B read
  float* wpad = (float*)(uni + 17408);     // [17408,22144) prologue write / A read
  u16* Wos = (u16*)(uni + 22144);          // [22144,26496) prologue write / B read
  float2* offsL = (float2*)(uni + 17408);  // [17408,21504) B write / C read (wpad dead)
  float* part = (float*)uni;               // [0,20736)   C (Ge dead)
  u16* xds_bf = (u16*)(uni + 20736);       // [20736,37632) C (Wos dead)
  int tid = threadIdx.x;
  // stage weights into conflict-free layouts
  for (int i = 0; i < 3; ++i) {
    int lin = (i << 9) + tid;
    if (lin < 1152) {
      int c = lin / 9, k = lin - 9 * c;
      wpad[(c >> 4) * 148 + k * 16 + (c & 15)] = w9[lin];
    }
  }
  for (int i = 0; i < 4; ++i) {
    int idx = (i << 9) + tid;  // 2048 = 16o x 128c
    int o = idx >> 7, c = idx & 127;
    Wos[o * 136 + c] = fbf(offw[idx]);
  }
  int blk = blockIdx.x;
  int b = blk >> 8;
  int l0 = (blk & 255) << 6;
  __syncthreads();
  // ---- Phase A: dwconv2 + LN + GELU ----
  {
    int p2 = tid >> 3, g2 = tid & 7;
    int l = l0 + p2, hh = l >> 7, ww = l & 127;
    const u16* bb2 = xc + (((long)(b << 3) + g2) << 18);
    float acc[16];
    {
      const float4* bp = (const float4*)&bias[g2 << 4];
      float4 b0 = bp[0], b1 = bp[1], b2 = bp[2], b3 = bp[3];
      acc[0] = b0.x;  acc[1] = b0.y;  acc[2] = b0.z;  acc[3] = b0.w;
      acc[4] = b1.x;  acc[5] = b1.y;  acc[6] = b1.z;  acc[7] = b1.w;
      acc[8] = b2.x;  acc[9] = b2.y;  acc[10] = b2.z; acc[11] = b2.w;
      acc[12] = b3.x; acc[13] = b3.y; acc[14] = b3.z; acc[15] = b3.w;
    }
#pragma unroll
    for (int ky = -1; ky <= 1; ++ky) {
      int y = hh + ky;
      if ((unsigned)y >= 128u) continue;
#pragma unroll
      for (int kx = -1; kx <= 1; ++kx) {
        int x = ww + kx;
        if ((unsigned)x >= 128u) continue;
        int k = (ky + 1) * 3 + (kx + 1);
        const u16* tp = bb2 + ((((y << 7) + x)) << 4);
        uint4 v0 = *(const uint4*)tp;
        uint4 v1 = *(const uint4*)(tp + 8);
        u32 vv[8] = {v0.x, v0.y, v0.z, v0.w, v1.x, v1.y, v1.z, v1.w};
        const float* wp = &wpad[g2 * 148 + k * 16];
        float4 w0 = *(const float4*)wp;
        float4 w1 = *(const float4*)(wp + 4);
        float4 w2 = *(const float4*)(wp + 8);
        float4 w3 = *(const float4*)(wp + 12);
        float wf[16] = {w0.x, w0.y, w0.z, w0.w, w1.x, w1.y, w1.z, w1.w,
                        w2.x, w2.y, w2.z, w2.w, w3.x, w3.y, w3.z, w3.w};
#pragma unroll
        for (int cc = 0; cc < 16; ++cc) {
          float xv = (cc & 1) ? hi16(vv[cc >> 1]) : lo16(vv[cc >> 1]);
          acc[cc] = fmaf(wf[cc], xv, acc[cc]);
        }
      }
    }
    // LN stats: partial over 16 ch, reduce across the 8 lanes sharing pixel
    float sum = 0.f, ssum = 0.f;
#pragma unroll
    for (int cc = 0; cc < 16; ++cc) { sum += acc[cc]; ssum = fmaf(acc[cc], acc[cc], ssum); }
#pragma unroll
    for (int off = 1; off < 8; off <<= 1) {
      sum += __shfl_xor(sum, off);
      ssum += __shfl_xor(ssum, off);
    }
    float m = sum * (1.f / 128.f);
    float r = rsqrtf(ssum * (1.f / 128.f) - m * m + 1e-6f);
    // LN + GELU -> bf16 -> Ge[p2][g2*16..+15]; gamma/beta from global (L1)
    float gf[16], bf_[16];
    {
      const float4* gp = (const float4*)&g[g2 << 4];
      const float4* bp = (const float4*)&bt[g2 << 4];
#pragma unroll
      for (int q = 0; q < 4; ++q) {
        float4 gq = gp[q];
        float4 bq = bp[q];
        gf[(q << 2) + 0] = gq.x; gf[(q << 2) + 1] = gq.y;
        gf[(q << 2) + 2] = gq.z; gf[(q << 2) + 3] = gq.w;
        bf_[(q << 2) + 0] = bq.x; bf_[(q << 2) + 1] = bq.y;
        bf_[(q << 2) + 2] = bq.z; bf_[(q << 2) + 3] = bq.w;
      }
    }
    u32 pk[8];
#pragma unroll
    for (int jj = 0; jj < 8; ++jj) {
      u16 h2[2];
#pragma unroll
      for (int e = 0; e < 2; ++e) {
        int cc = 2 * jj + e;
        float xn = fmaf((acc[cc] - m) * r, gf[cc], bf_[cc]);
        h2[e] = fbf(0.5f * xn * (1.f + erff(xn * 0.70710678118f)));
      }
      pk[jj] = (u32)h2[0] | ((u32)h2[1] << 16);
    }
    u16* row = &Ge[p2 * 136 + (g2 << 4)];
    *(uint4*)row = make_uint4(pk[0], pk[1], pk[2], pk[3]);
    *(uint4*)(row + 8) = make_uint4(pk[4], pk[5], pk[6], pk[7]);
  }
  __syncthreads();
  // ---- Phase B: offset projection (waves 0-3, 16 pixels each) ----
  {
    int w = tid >> 6, lane = tid & 63;
    if (w < 4) {
      int mrow = lane & 15, quad = lane >> 4;
      f32x4 acc0 = (f32x4){0.f, 0.f, 0.f, 0.f};
#pragma unroll
      for (int kb = 0; kb < 4; ++kb) {
        int cb = (kb << 5) + (quad << 3);
        bf16x8 af = ld_bf8(&Wos[mrow * 136 + cb]);
        bf16x8 bfr = ld_bf8(&Ge[((w << 4) + mrow) * 136 + cb]);
        acc0 = __builtin_amdgcn_mfma_f32_16x16x32_bf16(af, bfr, acc0, 0, 0, 0);
      }
      // D: col(lane&15)=pixel, row(quad*4+reg)=o; groups g0=2q (x,y), g1=2q+1
      int p = (w << 4) + mrow;
      int o0 = quad << 2;
      offsL[(p << 3) + (quad << 1)] = make_float2(acc0[0] + offb[o0], acc0[1] + offb[o0 + 1]);
      offsL[(p << 3) + (quad << 1) + 1] = make_float2(acc0[2] + offb[o0 + 2], acc0[3] + offb[o0 + 3]);
    }
  }
  __syncthreads();
  // ---- Phase C: DCN gather + x_proj + stores ----
  int p = tid & 63, gg = tid >> 6;
  int l = l0 + p, hh = l >> 7, ww = l & 127;
  float2 off = offsL[(p << 3) + gg];
  __syncthreads();  // offsL consumed; part/xds_bf may now overwrite it
  float px = (float)ww + off.x, py = (float)hh + off.y;
  float x0f = floorf(px), y0f = floorf(py);
  float wx = px - x0f, wy = py - y0f;
  int ix = (int)x0f, iy = (int)y0f;
  int x0c = min(max(ix, 0), 127), x1c = min(max(ix + 1, 0), 127);
  int y0c = min(max(iy, 0), 127), y1c = min(max(iy + 1, 0), 127);
  float vx0 = ((unsigned)ix < 128u) ? 1.f : 0.f;
  float vx1 = ((unsigned)(ix + 1) < 128u) ? 1.f : 0.f;
  float vy0 = ((unsigned)iy < 128u) ? 1.f : 0.f;
  float vy1 = ((unsigned)(iy + 1) < 128u) ? 1.f : 0.f;
  float wt4[4] = {(1.f - wy) * (1.f - wx) * vy0 * vx0,
                  (1.f - wy) * wx * vy0 * vx1,
                  wy * (1.f - wx) * vy1 * vx0,
                  wy * wx * vy1 * vx1};
  const u16* bbase = xc + (((long)(b << 3) + gg) << 18);
  const u16* r0p = bbase + ((((y0c << 7) + x0c)) << 4);
  const u16* r1p = bbase + ((((y1c << 7) + x0c)) << 4);
  uint4 q0 = ((const uint4*)r0p)[0];
  uint4 q1 = ((const uint4*)r0p)[1];
  uint4 q2 = ((const uint4*)r0p)[2];
  uint4 q3 = ((const uint4*)r0p)[3];
  uint4 q4 = ((const uint4*)r1p)[0];
  uint4 q5 = ((const uint4*)r1p)[1];
  uint4 q6 = ((const uint4*)r1p)[2];
  uint4 q7 = ((const uint4*)r1p)[3];
  bool adj = (x1c != x0c);
  u32 t0[8] = {q0.x, q0.y, q0.z, q0.w, q1.x, q1.y, q1.z, q1.w};
  u32 t1[8] = {adj ? q2.x : q0.x, adj ? q2.y : q0.y, adj ? q2.z : q0.z, adj ? q2.w : q0.w,
               adj ? q3.x : q1.x, adj ? q3.y : q1.y, adj ? q3.z : q1.z, adj ? q3.w : q1.w};
  u32 t2[8] = {q4.x, q4.y, q4.z, q4.w, q5.x, q5.y, q5.z, q5.w};
  u32 t3[8] = {adj ? q6.x : q4.x, adj ? q6.y : q4.y, adj ? q6.z : q4.z, adj ? q6.w : q4.w,
               adj ? q7.x : q5.x, adj ? q7.y : q5.y, adj ? q7.z : q5.z, adj ? q7.w : q5.w};
  float acc[16];
#pragma unroll
  for (int ch = 0; ch < 16; ++ch) {
    float v0 = (ch & 1) ? hi16(t0[ch >> 1]) : lo16(t0[ch >> 1]);
    float v1 = (ch & 1) ? hi16(t1[ch >> 1]) : lo16(t1[ch >> 1]);
    float v2 = (ch & 1) ? hi16(t2[ch >> 1]) : lo16(t2[ch >> 1]);
    float v3 = (ch & 1) ? hi16(t3[ch >> 1]) : lo16(t3[ch >> 1]);
    float a = fmaf(wt4[0], v0, wt4[1] * v1);
    a = fmaf(wt4[2], v2, a);
    acc[ch] = fmaf(wt4[3], v3, a);
  }
  {
    u32 pk[8];
#pragma unroll
    for (int j = 0; j < 8; ++j)
      pk[j] = (u32)fbf(acc[2 * j]) | ((u32)fbf(acc[2 * j + 1]) << 16);
    u16* row = &xds_bf[p * 132 + (gg << 4)];
#pragma unroll
    for (int q = 0; q < 4; ++q)
      *(uint2*)(row + (q << 2)) = make_uint2(pk[2 * q], pk[2 * q + 1]);
  }
  // x_proj partials (part overlays Ge -- dead since Phase B)
  {
    int ggu = __builtin_amdgcn_readfirstlane(gg);
    const float* wb = xpw + (ggu << 4);
    int pbase = p * 81 + gg;
#pragma unroll
    for (int r = 0; r < 10; ++r) {
      const float* wr = wb + (r << 7);
      float s = 0.f;
#pragma unroll
      for (int ch = 0; ch < 16; ++ch) s = fmaf(wr[ch], acc[ch], s);
      part[pbase + (r << 3)] = s;
    }
  }
  __syncthreads();
  {
    int task = tid;
#pragma unroll
    for (int pass = 0; pass < 2; ++pass, task += 512) {
      if (task < 640) {
        int r = task >> 6, p2 = task & 63;
        const float* pp = &part[p2 * 81 + (r << 3)];
        float s = ((pp[0] + pp[1]) + (pp[2] + pp[3])) + ((pp[4] + pp[5]) + (pp[6] + pp[7]));
        if (r < 8) xdblT[(r << 6) + p2] = s;
        else if (r == 8) Bsb[((long)b << 14) + l0 + p2] = s;
        else Csb[((long)b << 14) + l0 + p2] = s;
      }
    }
  }
#pragma unroll
  for (int it = 0; it < 2; ++it) {
    int task = (it << 9) + tid;
    int cc = task >> 3, t = task & 7;
    u32 pk[4];
#pragma unroll
    for (int jj = 0; jj < 4; ++jj) {
      u16 a0 = xds_bf[((t << 3) + 2 * jj + 0) * 132 + cc];
      u16 a1 = xds_bf[((t << 3) + 2 * jj + 1) * 132 + cc];
      pk[jj] = (u32)a0 | ((u32)a1 << 16);
    }
    *(uint4*)&xs[(((long)(b << 7) + cc) << 14) + l0 + (t << 3)] =
        make_uint4(pk[0], pk[1], pk[2], pk[3]);
  }
  __syncthreads();  // xdblT visible
  {
    int dd = tid >> 3, t = tid & 7;
    float4 a0 = *(const float4*)&dtw[dd << 3];
    float4 a1 = *(const float4*)&dtw[(dd << 3) + 4];
    float4 b0 = *(const float4*)&dtw[(dd + 64) << 3];
    float4 b1 = *(const float4*)&dtw[((dd + 64) << 3) + 4];
    float wr0[8] = {a0.x, a0.y, a0.z, a0.w, a1.x, a1.y, a1.z, a1.w};
    float wr1[8] = {b0.x, b0.y, b0.z, b0.w, b1.x, b1.y, b1.z, b1.w};
    float y0[8], y1[8];
#pragma unroll
    for (int j = 0; j < 8; ++j) { y0[j] = 0.f; y1[j] = 0.f; }
#pragma unroll
    for (int rr = 0; rr < 8; ++rr) {
      float w0 = wr0[rr], w1 = wr1[rr];
      const float* xr = &xdblT[(rr << 6) + (t << 3)];
      float4 xa = *(const float4*)xr;
      float4 xb = *(const float4*)(xr + 4);
      float xv[8] = {xa.x, xa.y, xa.z, xa.w, xb.x, xb.y, xb.z, xb.w};
#pragma unroll
      for (int j = 0; j < 8; ++j) {
        y0[j] = fmaf(w0, xv[j], y0[j]);
        y1[j] = fmaf(w1, xv[j], y1[j]);
      }
    }
    u32 pk0[4], pk1[4];
#pragma unroll
    for (int jj = 0; jj < 4; ++jj) {
      pk0[jj] = (u32)fbf(y0[2 * jj]) | ((u32)fbf(y0[2 * jj + 1]) << 16);
      pk1[jj] = (u32)fbf(y1[2 * jj]) | ((u32)fbf(y1[2 * jj + 1]) << 16);
    }
    *(uint4*)&dts[(((long)(b << 7) + dd) << 14) + l0 + (t << 3)] =
        make_uint4(pk0[0], pk0[1], pk0[2], pk0[3]);
    *(uint4*)&dts[(((long)(b << 7) + dd + 64) << 14) + l0 + (t << 3)] =
        make_uint4(pk1[0], pk1[1], pk1[2], pk1[3]);
  }
}

// ---- K5: selective scan, shfl-based block scan, cheap softplus -------------
__global__ __launch_bounds__(1024) void k_scan(u16* __restrict__ xy,
                                               const u16* __restrict__ dts16,
                                               const float* __restrict__ Bsb,
                                               const float* __restrict__ Csb,
                                               const float* __restrict__ A_logs,
                                               const float* __restrict__ Dsv,
                                               const float* __restrict__ dtbv) {
  __shared__ float swp[16], swe[16];
  int bd = blockIdx.x;
  int b = bd >> 7, d = bd & 127;
  float Ad = -__expf(A_logs[d]);
  float dtb = dtbv[d];
  float Dd = Dsv[d];
  int t = threadIdx.x;
  int lane = t & 63, wid = t >> 6;
  long base = ((long)bd << 14) + (t << 4);
  long bb = ((long)b << 14) + (t << 4);
  const uint4* pz4 = (const uint4*)(dts16 + base);
  const uint4* px4 = (const uint4*)(xy + base);
  const float4* pB = (const float4*)(Bsb + bb);
  const float4* pC = (const float4*)(Csb + bb);
  uint4 zA = pz4[0], zB = pz4[1];
  uint4 xA = px4[0], xB = px4[1];
  u32 zw[8] = {zA.x, zA.y, zA.z, zA.w, zB.x, zB.y, zB.z, zB.w};
  u32 xw[8] = {xA.x, xA.y, xA.z, xA.w, xB.x, xB.y, xB.z, xB.w};
  float E = 0.f, P = 1.f;
#pragma unroll
  for (int q = 0; q < 4; ++q) {
    float4 B4 = pB[q];
    float Bq[4] = {B4.x, B4.y, B4.z, B4.w};
#pragma unroll
    for (int j = 0; j < 4; ++j) {
      int k = (q << 2) + j;
      float z = (k & 1) ? hi16(zw[k >> 1]) : lo16(zw[k >> 1]);
      float xv = (k & 1) ? hi16(xw[k >> 1]) : lo16(xw[k >> 1]);
      float delta = softplusf(z + dtb);
      float a = __expf(delta * Ad);
      E = fmaf(a, E, delta * Bq[j] * xv);
      P *= a;
    }
  }
#pragma unroll
  for (int off = 1; off < 64; off <<= 1) {
    float Pp = __shfl_up(P, off);
    float Ep = __shfl_up(E, off);
    if (lane >= off) { E = fmaf(P, Ep, E); P *= Pp; }
  }
  if (lane == 63) { swp[wid] = P; swe[wid] = E; }
  __syncthreads();
  if (t < 16) {
    float p2 = swp[t], e2 = swe[t];
#pragma unroll
    for (int off = 1; off < 16; off <<= 1) {
      float pp = __shfl_up(p2, off);
      float ee = __shfl_up(e2, off);
      if (t >= off) { e2 = fmaf(p2, ee, e2); p2 *= pp; }
    }
    swp[t] = p2; swe[t] = e2;
  }
  __syncthreads();
  float hw = (wid == 0) ? 0.f : swe[wid - 1];
  float Pex = __shfl_up(P, 1);
  float Eex = __shfl_up(E, 1);
  if (lane == 0) { Pex = 1.f; Eex = 0.f; }
  float h = fmaf(Pex, hw, Eex);
  u32 ypk[8];
#pragma unroll
  for (int q = 0; q < 4; ++q) {
    float4 B4 = pB[q];
    float4 C4 = pC[q];
    float Bq[4] = {B4.x, B4.y, B4.z, B4.w};
    float Cq[4] = {C4.x, C4.y, C4.z, C4.w};
#pragma unroll
    for (int j = 0; j < 4; ++j) {
      int k = (q << 2) + j;
      float z = (k & 1) ? hi16(zw[k >> 1]) : lo16(zw[k >> 1]);
      float xv = (k & 1) ? hi16(xw[k >> 1]) : lo16(xw[k >> 1]);
      float delta = softplusf(z + dtb);
      float a = __expf(delta * Ad);
      h = fmaf(a, h, delta * Bq[j] * xv);
      u16 yb = fbf(fmaf(Dd, xv, h * Cq[j]));
      if ((k & 1) == 0) ypk[k >> 1] = yb; else ypk[k >> 1] |= (u32)yb << 16;
    }
  }
  uint4* py = (uint4*)(xy + base);
  py[0] = make_uint4(ypk[0], ypk[1], ypk[2], ypk[3]);
  py[1] = make_uint4(ypk[4], ypk[5], ypk[6], ypk[7]);
}

// ---- K7: out_proj MFMA GEMM + fused LN epilogue (f32 out, [b,o,l]) ---------
__global__ __launch_bounds__(256) void k_outproj(const u16* __restrict__ y,
                                                 const float* __restrict__ W2,
                                                 const float* __restrict__ g,
                                                 const float* __restrict__ s12,
                                                 float* __restrict__ out) {
  __shared__ __align__(16) u16 Ws[128 * 136];  // [o][c] bf16 of W2*gamma
  __shared__ __align__(16) u16 Ys[64 * 136];   // [l][c] bf16 (y^T tile)
  __shared__ float ps[4][64], pss[4][64];
  __shared__ float mean_s[64], rstd_s[64];
  int tid = threadIdx.x;
  int b = blockIdx.x >> 8;
  int l0 = (blockIdx.x & 255) << 6;
  for (int i = 0; i < 16; ++i) {
    int idx = (i << 8) + tid;
    int o = idx >> 5, c4 = (idx & 31) << 2;
    float4 w4 = *(const float4*)&W2[(o << 7) + c4];
    ushort4 s;
    s.x = fbf(w4.x * g[c4]);     s.y = fbf(w4.y * g[c4 + 1]);
    s.z = fbf(w4.z * g[c4 + 2]); s.w = fbf(w4.w * g[c4 + 3]);
    *(ushort4*)&Ws[o * 136 + c4] = s;
  }
  for (int i = 0; i < 4; ++i) {
    int idx = (i << 8) + tid;
    int c = idx >> 3, lq = (idx & 7) << 3;
    uint4 v = *(const uint4*)&y[(((long)(b << 7) + c) << 14) + l0 + lq];
    u32 vv[4] = {v.x, v.y, v.z, v.w};
#pragma unroll
    for (int r = 0; r < 8; ++r)
      Ys[(lq + r) * 136 + c] = (u16)((r & 1) ? (vv[r >> 1] >> 16) : (vv[r >> 1] & 0xffffu));
  }
  __syncthreads();
  {
    int l = tid & 63, q = tid >> 6;
    const u16* row = &Ys[l * 136 + (q << 5)];
    float s = 0.f, ss = 0.f;
#pragma unroll 8
    for (int c = 0; c < 32; ++c) { float v = bfu(row[c]); s += v; ss = fmaf(v, v, ss); }
    ps[q][l] = s; pss[q][l] = ss;
  }
  __syncthreads();
  if (tid < 64) {
    float s = ps[0][tid] + ps[1][tid] + ps[2][tid] + ps[3][tid];
    float ss = pss[0][tid] + pss[1][tid] + pss[2][tid] + pss[3][tid];
    float m = s * (1.f / 128.f);
    mean_s[tid] = m;
    rstd_s[tid] = rsqrtf(ss * (1.f / 128.f) - m * m + 1e-6f);
  }
  __syncthreads();
  int w = tid >> 6, lane = tid & 63;
  int mrow = lane & 15, quad = lane >> 4;
  f32x4 acc[2][4];
#pragma unroll
  for (int ot = 0; ot < 2; ++ot)
#pragma unroll
    for (int lt = 0; lt < 4; ++lt) acc[ot][lt] = (f32x4){0.f, 0.f, 0.f, 0.f};
#pragma unroll
  for (int kb = 0; kb < 4; ++kb) {
    int c0 = (kb << 5) + (quad << 3);
    bf16x8 af[2], bfr[4];
#pragma unroll
    for (int ot = 0; ot < 2; ++ot)
      af[ot] = ld_bf8(&Ws[((w << 5) + (ot << 4) + mrow) * 136 + c0]);
#pragma unroll
    for (int lt = 0; lt < 4; ++lt)
      bfr[lt] = ld_bf8(&Ys[((lt << 4) + mrow) * 136 + c0]);
#pragma unroll
    for (int ot = 0; ot < 2; ++ot)
#pragma unroll
      for (int lt = 0; lt < 4; ++lt)
        acc[ot][lt] = __builtin_amdgcn_mfma_f32_16x16x32_bf16(af[ot], bfr[lt], acc[ot][lt], 0, 0, 0);
  }
  float s1r[2][4], s2r[2][4];
#pragma unroll
  for (int ot = 0; ot < 2; ++ot)
#pragma unroll
    for (int r = 0; r < 4; ++r) {
      int o = (w << 5) + (ot << 4) + (quad << 2) + r;
      s1r[ot][r] = s12[o];
      s2r[ot][r] = s12[128 + o];
    }
#pragma unroll
  for (int ot = 0; ot < 2; ++ot)
#pragma unroll
    for (int lt = 0; lt < 4; ++lt) {
      int lcol = (lt << 4) + mrow;
      float mv = mean_s[lcol], rv = rstd_s[lcol];
      int obase = (w << 5) + (ot << 4) + (quad << 2);
#pragma unroll
      for (int r = 0; r < 4; ++r) {
        float v = fmaf(rv, acc[ot][lt][r] - mv * s2r[ot][r], s1r[ot][r]);
        out[(((long)(b << 7) + obase + r) << 14) + l0 + lcol] = v;
      }
    }
}

extern "C" void kernel_launch(void* const* d_in, const int* in_sizes, int n_in,
                              void* d_out, int out_size, void* d_ws, size_t ws_size,
                              hipStream_t stream) {
  const float* x         = (const float*)d_in[0];
  const float* in_proj_w = (const float*)d_in[1];
  const float* conv2d_w  = (const float*)d_in[2];
  const float* conv2d_b  = (const float*)d_in[3];
  const float* dw_w      = (const float*)d_in[4];
  const float* dw_b      = (const float*)d_in[5];
  const float* dw_ln_g   = (const float*)d_in[6];
  const float* dw_ln_b   = (const float*)d_in[7];
  const float* off_w     = (const float*)d_in[8];
  const float* off_b     = (const float*)d_in[9];
  const float* x_proj_w  = (const float*)d_in[10];
  const float* dt_w      = (const float*)d_in[11];
  const float* dt_b      = (const float*)d_in[12];
  const float* A_logs    = (const float*)d_in[13];
  const float* Ds        = (const float*)d_in[14];
  const float* out_ln_g  = (const float*)d_in[15];
  const float* out_ln_b  = (const float*)d_in[16];
  const float* out_proj_w= (const float*)d_in[17];
  float* out = (float*)d_out;

  u16* A  = (u16*)d_ws;            // xin_cl -> xs[b,c,l] -> y[b,c,l]
  u16* Bx = A + 8388608;           // xc group-blocked [b][g][y][x][c16]
  u16* Dd = Bx + 8388608;          // dts[b,c,l]
  float* Bsb   = (float*)(Dd + 8388608);
  float* Csb   = Bsb + 65536;
  float* s12   = Csb + 65536;

  hipLaunchKernelGGL(k_inproj, dim3(1025), dim3(256), 0, stream, x, in_proj_w, A,
                     out_proj_w, out_ln_g, out_ln_b, s12);
  hipLaunchKernelGGL(k_dwconv, dim3(4096), dim3(256), 0, stream, A, conv2d_w, conv2d_b, Bx);
  hipLaunchKernelGGL(k_dcnoff, dim3(1024), dim3(512), 0, stream, Bx, dw_w, dw_b,
                     dw_ln_g, dw_ln_b, off_w, off_b, x_proj_w, dt_w, A, Dd, Bsb, Csb);
  hipLaunchKernelGGL(k_scan, dim3(512), dim3(1024), 0, stream, A, Dd, Bsb, Csb, A_logs, Ds, dt_b);
  hipLaunchKernelGGL(k_outproj, dim3(1024), dim3(256), 0, stream, A, out_proj_w, out_ln_g, s12, out);
}

// Round 9
// 204.638 us; speedup vs baseline: 1.0764x; 1.0764x over previous
//
#include <hip/hip_runtime.h>
#include <hip/hip_bf16.h>

typedef unsigned short u16;
typedef unsigned int u32;
typedef __bf16 bf16x8 __attribute__((ext_vector_type(8)));
typedef float f32x4 __attribute__((ext_vector_type(4)));

__device__ __forceinline__ float bfu(u16 u) { return __uint_as_float(((u32)u) << 16); }
__device__ __forceinline__ u16 fbf(float f) {
  __hip_bfloat16 h = __float2bfloat16(f);
  return *reinterpret_cast<u16*>(&h);
}
__device__ __forceinline__ float softplusf(float z) {
  float t = __expf(z);
  return (z > 20.f) ? z : __logf(1.f + t);
}
__device__ __forceinline__ float lo16(u32 p) { return __uint_as_float(p << 16); }
__device__ __forceinline__ float hi16(u32 p) { return __uint_as_float(p & 0xffff0000u); }
__device__ __forceinline__ bf16x8 ld_bf8(const u16* p) {
  union { uint4 u; bf16x8 v; } c;
  c.u = *(const uint4*)p;
  return c.v;
}

// xc layout is GROUP-BLOCKED channels-last: [b][g][y][x][c16] (u16 units:
// base + ((b*8+g)<<18) + ((y*128+x)<<4) + c).

// ---- K1: in_proj MFMA GEMM + (block 1024) k_sums fold ----------------------
__global__ __launch_bounds__(256) void k_inproj(const float* __restrict__ X,
                                                const float* __restrict__ W,
                                                u16* __restrict__ out,
                                                const float* __restrict__ W2,
                                                const float* __restrict__ gO,
                                                const float* __restrict__ bO,
                                                float* __restrict__ s12) {
  __shared__ __align__(16) u16 Ws[128 * 136];  // [o][c] bf16
  __shared__ __align__(16) u16 Xs[64 * 136];   // [l][c] bf16 (X^T tile)
  int tid = threadIdx.x;
  if (blockIdx.x == 1024) {  // folded k_sums
    if (tid < 128) {
      int o = tid;
      float s1 = 0.f, s2 = 0.f;
      for (int c = 0; c < 128; ++c) {
        float w = W2[(o << 7) + c];
        s1 = fmaf(w, bO[c], s1);
        s2 = fmaf(w, gO[c], s2);
      }
      s12[o] = s1;
      s12[128 + o] = s2;
    }
    return;
  }
  int b = blockIdx.x >> 8;
  int l0 = (blockIdx.x & 255) << 6;
  for (int i = 0; i < 16; ++i) {
    int idx = (i << 8) + tid;
    int o = idx >> 5, c4 = (idx & 31) << 2;
    float4 w4 = *(const float4*)&W[(o << 7) + c4];
    ushort4 s;
    s.x = fbf(w4.x); s.y = fbf(w4.y); s.z = fbf(w4.z); s.w = fbf(w4.w);
    *(ushort4*)&Ws[o * 136 + c4] = s;
  }
  for (int i = 0; i < 8; ++i) {
    int idx = (i << 8) + tid;
    int c = idx >> 4, lq = (idx & 15) << 2;
    float4 x4 = *(const float4*)&X[(((long)(b << 7) + c) << 14) + l0 + lq];
    Xs[(lq + 0) * 136 + c] = fbf(x4.x);
    Xs[(lq + 1) * 136 + c] = fbf(x4.y);
    Xs[(lq + 2) * 136 + c] = fbf(x4.z);
    Xs[(lq + 3) * 136 + c] = fbf(x4.w);
  }
  __syncthreads();
  int w = tid >> 6, lane = tid & 63;
  int mrow = lane & 15, quad = lane >> 4;
  f32x4 acc[2][4];
#pragma unroll
  for (int ot = 0; ot < 2; ++ot)
#pragma unroll
    for (int lt = 0; lt < 4; ++lt) acc[ot][lt] = (f32x4){0.f, 0.f, 0.f, 0.f};
#pragma unroll
  for (int kb = 0; kb < 4; ++kb) {
    int c0 = (kb << 5) + (quad << 3);
    bf16x8 af[2], bfr[4];
#pragma unroll
    for (int ot = 0; ot < 2; ++ot)
      af[ot] = ld_bf8(&Ws[((w << 5) + (ot << 4) + mrow) * 136 + c0]);
#pragma unroll
    for (int lt = 0; lt < 4; ++lt)
      bfr[lt] = ld_bf8(&Xs[((lt << 4) + mrow) * 136 + c0]);
#pragma unroll
    for (int ot = 0; ot < 2; ++ot)
#pragma unroll
      for (int lt = 0; lt < 4; ++lt)
        acc[ot][lt] = __builtin_amdgcn_mfma_f32_16x16x32_bf16(af[ot], bfr[lt], acc[ot][lt], 0, 0, 0);
  }
#pragma unroll
  for (int ot = 0; ot < 2; ++ot)
#pragma unroll
    for (int lt = 0; lt < 4; ++lt) {
      int l = l0 + (lt << 4) + mrow;
      int o = (w << 5) + (ot << 4) + (quad << 2);
      ushort4 s;
      s.x = fbf(acc[ot][lt][0]); s.y = fbf(acc[ot][lt][1]);
      s.z = fbf(acc[ot][lt][2]); s.w = fbf(acc[ot][lt][3]);
      *(ushort4*)&out[(((long)(b << 14) + l) << 7) + o] = s;
    }
}

// ---- K2: depthwise 3x3 conv + SiLU; in [l][c128], out group-blocked --------
__global__ __launch_bounds__(256) void k_dwconv(const u16* __restrict__ in,
                                                const float* __restrict__ w9,
                                                const float* __restrict__ bias,
                                                u16* __restrict__ out) {
  __shared__ float wsT[9][128];
  __shared__ float bs[128];
  int tid = threadIdx.x;
  for (int i = 0; i < 5; ++i) {
    int lin = (i << 8) + tid;
    if (lin < 1152) { int c = lin / 9, k = lin - 9 * c; wsT[k][c] = w9[lin]; }
  }
  if (tid < 128) bs[tid] = bias[tid];
  __syncthreads();
  int blk = blockIdx.x;
  int b = blk >> 10;
  int s = blk & 1023;
  int h = s >> 3;
  int w = ((s & 7) << 4) + (tid >> 4);
  int c0 = (tid & 15) << 3;
  const u16* bbase = in + ((long)b << 21);
  float acc[8];
  {
    float4 b0 = *(const float4*)&bs[c0];
    float4 b1 = *(const float4*)&bs[c0 + 4];
    acc[0] = b0.x; acc[1] = b0.y; acc[2] = b0.z; acc[3] = b0.w;
    acc[4] = b1.x; acc[5] = b1.y; acc[6] = b1.z; acc[7] = b1.w;
  }
#pragma unroll
  for (int ky = -1; ky <= 1; ++ky) {
    int y = h + ky;
    if ((unsigned)y >= 128u) continue;
#pragma unroll
    for (int kx = -1; kx <= 1; ++kx) {
      int x = w + kx;
      if ((unsigned)x >= 128u) continue;
      int k = (ky + 1) * 3 + (kx + 1);
      uint4 v = *(const uint4*)(bbase + ((((y << 7) + x)) << 7) + c0);
      float4 w0 = *(const float4*)&wsT[k][c0];
      float4 w1 = *(const float4*)&wsT[k][c0 + 4];
      u32 vv[4] = {v.x, v.y, v.z, v.w};
      float wf[8] = {w0.x, w0.y, w0.z, w0.w, w1.x, w1.y, w1.z, w1.w};
#pragma unroll
      for (int cc = 0; cc < 8; ++cc) {
        float xv = (cc & 1) ? hi16(vv[cc >> 1]) : lo16(vv[cc >> 1]);
        acc[cc] = fmaf(wf[cc], xv, acc[cc]);
      }
    }
  }
#pragma unroll
  for (int cc = 0; cc < 8; ++cc) acc[cc] = acc[cc] / (1.f + __expf(-acc[cc]));
  int g4 = c0 >> 4, sub = c0 & 15;
  uint4 pkst;
  pkst.x = (u32)fbf(acc[0]) | ((u32)fbf(acc[1]) << 16);
  pkst.y = (u32)fbf(acc[2]) | ((u32)fbf(acc[3]) << 16);
  pkst.z = (u32)fbf(acc[4]) | ((u32)fbf(acc[5]) << 16);
  pkst.w = (u32)fbf(acc[6]) | ((u32)fbf(acc[7]) << 16);
  u16* po = out + (((long)(b << 3) + g4) << 18) + ((((h << 7) + w)) << 4) + sub;
  *(uint4*)po = pkst;
}

// ---- K3: FUSED dwconv#2 + LN + GELU + offset MFMA + DCN gather + x_proj ----
// v9 = v7 (51712B LDS, 3 blocks/CU -- the measured-best config) + XCD-aware
// bijective block swizzle (T1).  v8 proved the kernel is L2-capacity-bound:
// raising occupancy to 4 blocks/CU blew HBM traffic +50% (FETCH 38->57MB,
// WRITE 37->60MB) and cost 10us.  The swizzle gives each XCD a contiguous
// 128-tile band (64 image rows), so Phase-A halo taps and Phase-C gathers
// (offsets are ~0.01-scale, staying in-band) hit the XCD-local L2 instead
// of re-fetching from HBM.  1024 % 8 == 0 -> bijective.
__global__ __launch_bounds__(512, 6) void k_dcnoff(const u16* __restrict__ xc,
                                                   const float* __restrict__ w9,
                                                   const float* __restrict__ bias,
                                                   const float* __restrict__ g,
                                                   const float* __restrict__ bt,
                                                   const float* __restrict__ offw,
                                                   const float* __restrict__ offb,
                                                   const float* __restrict__ xpw,
                                                   const float* __restrict__ dtw,
                                                   u16* __restrict__ xs,
                                                   u16* __restrict__ dts,
                                                   float* __restrict__ Bsb,
                                                   float* __restrict__ Csb) {
  __shared__ __align__(16) char uni[26496];
  __shared__ __align__(16) float bsp[160], gsp[160], bshp[160];  // [g2*20+cc]
  __shared__ __align__(16) u16 xds_bf[64 * 132];  // [p][c] bf16
  __shared__ __align__(16) float xdblT[8 * 64];   // [r][p]
  __shared__ __align__(16) float2 offsL[64 * 8];  // [p][g]
  u16* Ge = (u16*)uni;
  float* wpad = (float*)(uni + 17408);
  u16* Wos = (u16*)(uni + 22144);
  float* part = (float*)uni;
  int tid = threadIdx.x;
  // stage weights into conflict-free layouts
  for (int i = 0; i < 3; ++i) {
    int lin = (i << 9) + tid;
    if (lin < 1152) {
      int c = lin / 9, k = lin - 9 * c;
      wpad[(c >> 4) * 148 + k * 16 + (c & 15)] = w9[lin];
    }
  }
  if (tid < 128) {
    int g2s = tid >> 4, ccs = tid & 15;
    bsp[g2s * 20 + ccs] = bias[tid];
    gsp[g2s * 20 + ccs] = g[tid];
    bshp[g2s * 20 + ccs] = bt[tid];
  }
  for (int i = 0; i < 4; ++i) {
    int idx = (i << 9) + tid;  // 2048 = 16o x 128c
    int o = idx >> 7, c = idx & 127;
    Wos[o * 136 + c] = fbf(offw[idx]);
  }
  // XCD-aware bijective swizzle: XCD x gets logical tiles [x*128,(x+1)*128)
  int orig = blockIdx.x;
  int blk = ((orig & 7) << 7) | (orig >> 3);
  int b = blk >> 8;
  int l0 = (blk & 255) << 6;
  __syncthreads();
  // ---- Phase A: dwconv2 + LN + GELU ----
  {
    int p2 = tid >> 3, g2 = tid & 7;
    int l = l0 + p2, hh = l >> 7, ww = l & 127;
    const u16* bb2 = xc + (((long)(b << 3) + g2) << 18);
    float acc[16];
    {
      const float* bp = &bsp[g2 * 20];
      float4 b0 = *(const float4*)bp;
      float4 b1 = *(const float4*)(bp + 4);
      float4 b2 = *(const float4*)(bp + 8);
      float4 b3 = *(const float4*)(bp + 12);
      acc[0] = b0.x;  acc[1] = b0.y;  acc[2] = b0.z;  acc[3] = b0.w;
      acc[4] = b1.x;  acc[5] = b1.y;  acc[6] = b1.z;  acc[7] = b1.w;
      acc[8] = b2.x;  acc[9] = b2.y;  acc[10] = b2.z; acc[11] = b2.w;
      acc[12] = b3.x; acc[13] = b3.y; acc[14] = b3.z; acc[15] = b3.w;
    }
#pragma unroll
    for (int ky = -1; ky <= 1; ++ky) {
      int y = hh + ky;
      if ((unsigned)y >= 128u) continue;
#pragma unroll
      for (int kx = -1; kx <= 1; ++kx) {
        int x = ww + kx;
        if ((unsigned)x >= 128u) continue;
        int k = (ky + 1) * 3 + (kx + 1);
        const u16* tp = bb2 + ((((y << 7) + x)) << 4);
        uint4 v0 = *(const uint4*)tp;
        uint4 v1 = *(const uint4*)(tp + 8);
        u32 vv[8] = {v0.x, v0.y, v0.z, v0.w, v1.x, v1.y, v1.z, v1.w};
        const float* wp = &wpad[g2 * 148 + k * 16];
        float4 w0 = *(const float4*)wp;
        float4 w1 = *(const float4*)(wp + 4);
        float4 w2 = *(const float4*)(wp + 8);
        float4 w3 = *(const float4*)(wp + 12);
        float wf[16] = {w0.x, w0.y, w0.z, w0.w, w1.x, w1.y, w1.z, w1.w,
                        w2.x, w2.y, w2.z, w2.w, w3.x, w3.y, w3.z, w3.w};
#pragma unroll
        for (int cc = 0; cc < 16; ++cc) {
          float xv = (cc & 1) ? hi16(vv[cc >> 1]) : lo16(vv[cc >> 1]);
          acc[cc] = fmaf(wf[cc], xv, acc[cc]);
        }
      }
    }
    // LN stats: partial over 16 ch, reduce across the 8 lanes sharing pixel
    float sum = 0.f, ssum = 0.f;
#pragma unroll
    for (int cc = 0; cc < 16; ++cc) { sum += acc[cc]; ssum = fmaf(acc[cc], acc[cc], ssum); }
#pragma unroll
    for (int off = 1; off < 8; off <<= 1) {
      sum += __shfl_xor(sum, off);
      ssum += __shfl_xor(ssum, off);
    }
    float m = sum * (1.f / 128.f);
    float r = rsqrtf(ssum * (1.f / 128.f) - m * m + 1e-6f);
    // LN + GELU -> bf16 -> Ge[p2][g2*16..+15]
    float gf[16], bf_[16];
    {
      const float* gp = &gsp[g2 * 20];
      const float* bp = &bshp[g2 * 20];
#pragma unroll
      for (int q = 0; q < 4; ++q) {
        float4 gq = *(const float4*)(gp + (q << 2));
        float4 bq = *(const float4*)(bp + (q << 2));
        gf[(q << 2) + 0] = gq.x; gf[(q << 2) + 1] = gq.y;
        gf[(q << 2) + 2] = gq.z; gf[(q << 2) + 3] = gq.w;
        bf_[(q << 2) + 0] = bq.x; bf_[(q << 2) + 1] = bq.y;
        bf_[(q << 2) + 2] = bq.z; bf_[(q << 2) + 3] = bq.w;
      }
    }
    u32 pk[8];
#pragma unroll
    for (int jj = 0; jj < 8; ++jj) {
      u16 h2[2];
#pragma unroll
      for (int e = 0; e < 2; ++e) {
        int cc = 2 * jj + e;
        float xn = fmaf((acc[cc] - m) * r, gf[cc], bf_[cc]);
        h2[e] = fbf(0.5f * xn * (1.f + erff(xn * 0.70710678118f)));
      }
      pk[jj] = (u32)h2[0] | ((u32)h2[1] << 16);
    }
    u16* row = &Ge[p2 * 136 + (g2 << 4)];
    *(uint4*)row = make_uint4(pk[0], pk[1], pk[2], pk[3]);
    *(uint4*)(row + 8) = make_uint4(pk[4], pk[5], pk[6], pk[7]);
  }
  __syncthreads();
  // ---- Phase B: offset projection (waves 0-3, 16 pixels each) ----
  {
    int w = tid >> 6, lane = tid & 63;
    if (w < 4) {
      int mrow = lane & 15, quad = lane >> 4;
      f32x4 acc0 = (f32x4){0.f, 0.f, 0.f, 0.f};
#pragma unroll
      for (int kb = 0; kb < 4; ++kb) {
        int cb = (kb << 5) + (quad << 3);
        bf16x8 af = ld_bf8(&Wos[mrow * 136 + cb]);
        bf16x8 bfr = ld_bf8(&Ge[((w << 4) + mrow) * 136 + cb]);
        acc0 = __builtin_amdgcn_mfma_f32_16x16x32_bf16(af, bfr, acc0, 0, 0, 0);
      }
      // D: col(lane&15)=pixel, row(quad*4+reg)=o; groups g0=2q (x,y), g1=2q+1
      int p = (w << 4) + mrow;
      int o0 = quad << 2;
      offsL[(p << 3) + (quad << 1)] = make_float2(acc0[0] + offb[o0], acc0[1] + offb[o0 + 1]);
      offsL[(p << 3) + (quad << 1) + 1] = make_float2(acc0[2] + offb[o0 + 2], acc0[3] + offb[o0 + 3]);
    }
  }
  __syncthreads();
  // ---- Phase C: DCN gather + x_proj + stores ----
  int p = tid & 63, gg = tid >> 6;
  int l = l0 + p, hh = l >> 7, ww = l & 127;
  float2 off = offsL[(p << 3) + gg];
  float px = (float)ww + off.x, py = (float)hh + off.y;
  float x0f = floorf(px), y0f = floorf(py);
  float wx = px - x0f, wy = py - y0f;
  int ix = (int)x0f, iy = (int)y0f;
  int x0c = min(max(ix, 0), 127), x1c = min(max(ix + 1, 0), 127);
  int y0c = min(max(iy, 0), 127), y1c = min(max(iy + 1, 0), 127);
  float vx0 = ((unsigned)ix < 128u) ? 1.f : 0.f;
  float vx1 = ((unsigned)(ix + 1) < 128u) ? 1.f : 0.f;
  float vy0 = ((unsigned)iy < 128u) ? 1.f : 0.f;
  float vy1 = ((unsigned)(iy + 1) < 128u) ? 1.f : 0.f;
  float wt4[4] = {(1.f - wy) * (1.f - wx) * vy0 * vx0,
                  (1.f - wy) * wx * vy0 * vx1,
                  wy * (1.f - wx) * vy1 * vx0,
                  wy * wx * vy1 * vx1};
  const u16* bbase = xc + (((long)(b << 3) + gg) << 18);
  const u16* r0p = bbase + ((((y0c << 7) + x0c)) << 4);
  const u16* r1p = bbase + ((((y1c << 7) + x0c)) << 4);
  uint4 q0 = ((const uint4*)r0p)[0];
  uint4 q1 = ((const uint4*)r0p)[1];
  uint4 q2 = ((const uint4*)r0p)[2];
  uint4 q3 = ((const uint4*)r0p)[3];
  uint4 q4 = ((const uint4*)r1p)[0];
  uint4 q5 = ((const uint4*)r1p)[1];
  uint4 q6 = ((const uint4*)r1p)[2];
  uint4 q7 = ((const uint4*)r1p)[3];
  bool adj = (x1c != x0c);
  u32 t0[8] = {q0.x, q0.y, q0.z, q0.w, q1.x, q1.y, q1.z, q1.w};
  u32 t1[8] = {adj ? q2.x : q0.x, adj ? q2.y : q0.y, adj ? q2.z : q0.z, adj ? q2.w : q0.w,
               adj ? q3.x : q1.x, adj ? q3.y : q1.y, adj ? q3.z : q1.z, adj ? q3.w : q1.w};
  u32 t2[8] = {q4.x, q4.y, q4.z, q4.w, q5.x, q5.y, q5.z, q5.w};
  u32 t3[8] = {adj ? q6.x : q4.x, adj ? q6.y : q4.y, adj ? q6.z : q4.z, adj ? q6.w : q4.w,
               adj ? q7.x : q5.x, adj ? q7.y : q5.y, adj ? q7.z : q5.z, adj ? q7.w : q5.w};
  float acc[16];
#pragma unroll
  for (int ch = 0; ch < 16; ++ch) {
    float v0 = (ch & 1) ? hi16(t0[ch >> 1]) : lo16(t0[ch >> 1]);
    float v1 = (ch & 1) ? hi16(t1[ch >> 1]) : lo16(t1[ch >> 1]);
    float v2 = (ch & 1) ? hi16(t2[ch >> 1]) : lo16(t2[ch >> 1]);
    float v3 = (ch & 1) ? hi16(t3[ch >> 1]) : lo16(t3[ch >> 1]);
    float a = fmaf(wt4[0], v0, wt4[1] * v1);
    a = fmaf(wt4[2], v2, a);
    acc[ch] = fmaf(wt4[3], v3, a);
  }
  {
    u32 pk[8];
#pragma unroll
    for (int j = 0; j < 8; ++j)
      pk[j] = (u32)fbf(acc[2 * j]) | ((u32)fbf(acc[2 * j + 1]) << 16);
    u16* row = &xds_bf[p * 132 + (gg << 4)];
#pragma unroll
    for (int q = 0; q < 4; ++q)
      *(uint2*)(row + (q << 2)) = make_uint2(pk[2 * q], pk[2 * q + 1]);
  }
  // x_proj partials (part overlays Ge/wpad head -- both dead since Phase B)
  {
    int ggu = __builtin_amdgcn_readfirstlane(gg);
    const float* wb = xpw + (ggu << 4);
    int pbase = p * 81 + gg;
#pragma unroll
    for (int r = 0; r < 10; ++r) {
      const float* wr = wb + (r << 7);
      float s = 0.f;
#pragma unroll
      for (int ch = 0; ch < 16; ++ch) s = fmaf(wr[ch], acc[ch], s);
      part[pbase + (r << 3)] = s;
    }
  }
  __syncthreads();
  {
    int task = tid;
#pragma unroll
    for (int pass = 0; pass < 2; ++pass, task += 512) {
      if (task < 640) {
        int r = task >> 6, p2 = task & 63;
        const float* pp = &part[p2 * 81 + (r << 3)];
        float s = ((pp[0] + pp[1]) + (pp[2] + pp[3])) + ((pp[4] + pp[5]) + (pp[6] + pp[7]));
        if (r < 8) xdblT[(r << 6) + p2] = s;
        else if (r == 8) Bsb[((long)b << 14) + l0 + p2] = s;
        else Csb[((long)b << 14) + l0 + p2] = s;
      }
    }
  }
#pragma unroll
  for (int it = 0; it < 2; ++it) {
    int task = (it << 9) + tid;
    int cc = task >> 3, t = task & 7;
    u32 pk[4];
#pragma unroll
    for (int jj = 0; jj < 4; ++jj) {
      u16 a0 = xds_bf[((t << 3) + 2 * jj + 0) * 132 + cc];
      u16 a1 = xds_bf[((t << 3) + 2 * jj + 1) * 132 + cc];
      pk[jj] = (u32)a0 | ((u32)a1 << 16);
    }
    *(uint4*)&xs[(((long)(b << 7) + cc) << 14) + l0 + (t << 3)] =
        make_uint4(pk[0], pk[1], pk[2], pk[3]);
  }
  __syncthreads();  // xdblT visible
  {
    int dd = tid >> 3, t = tid & 7;
    float4 a0 = *(const float4*)&dtw[dd << 3];
    float4 a1 = *(const float4*)&dtw[(dd << 3) + 4];
    float4 b0 = *(const float4*)&dtw[(dd + 64) << 3];
    float4 b1 = *(const float4*)&dtw[((dd + 64) << 3) + 4];
    float wr0[8] = {a0.x, a0.y, a0.z, a0.w, a1.x, a1.y, a1.z, a1.w};
    float wr1[8] = {b0.x, b0.y, b0.z, b0.w, b1.x, b1.y, b1.z, b1.w};
    float y0[8], y1[8];
#pragma unroll
    for (int j = 0; j < 8; ++j) { y0[j] = 0.f; y1[j] = 0.f; }
#pragma unroll
    for (int rr = 0; rr < 8; ++rr) {
      float w0 = wr0[rr], w1 = wr1[rr];
      const float* xr = &xdblT[(rr << 6) + (t << 3)];
      float4 xa = *(const float4*)xr;
      float4 xb = *(const float4*)(xr + 4);
      float xv[8] = {xa.x, xa.y, xa.z, xa.w, xb.x, xb.y, xb.z, xb.w};
#pragma unroll
      for (int j = 0; j < 8; ++j) {
        y0[j] = fmaf(w0, xv[j], y0[j]);
        y1[j] = fmaf(w1, xv[j], y1[j]);
      }
    }
    u32 pk0[4], pk1[4];
#pragma unroll
    for (int jj = 0; jj < 4; ++jj) {
      pk0[jj] = (u32)fbf(y0[2 * jj]) | ((u32)fbf(y0[2 * jj + 1]) << 16);
      pk1[jj] = (u32)fbf(y1[2 * jj]) | ((u32)fbf(y1[2 * jj + 1]) << 16);
    }
    *(uint4*)&dts[(((long)(b << 7) + dd) << 14) + l0 + (t << 3)] =
        make_uint4(pk0[0], pk0[1], pk0[2], pk0[3]);
    *(uint4*)&dts[(((long)(b << 7) + dd + 64) << 14) + l0 + (t << 3)] =
        make_uint4(pk1[0], pk1[1], pk1[2], pk1[3]);
  }
}

// ---- K5: selective scan, shfl-based block scan, cheap softplus -------------
__global__ __launch_bounds__(1024) void k_scan(u16* __restrict__ xy,
                                               const u16* __restrict__ dts16,
                                               const float* __restrict__ Bsb,
                                               const float* __restrict__ Csb,
                                               const float* __restrict__ A_logs,
                                               const float* __restrict__ Dsv,
                                               const float* __restrict__ dtbv) {
  __shared__ float swp[16], swe[16];
  int bd = blockIdx.x;
  int b = bd >> 7, d = bd & 127;
  float Ad = -__expf(A_logs[d]);
  float dtb = dtbv[d];
  float Dd = Dsv[d];
  int t = threadIdx.x;
  int lane = t & 63, wid = t >> 6;
  long base = ((long)bd << 14) + (t << 4);
  long bb = ((long)b << 14) + (t << 4);
  const uint4* pz4 = (const uint4*)(dts16 + base);
  const uint4* px4 = (const uint4*)(xy + base);
  const float4* pB = (const float4*)(Bsb + bb);
  const float4* pC = (const float4*)(Csb + bb);
  uint4 zA = pz4[0], zB = pz4[1];
  uint4 xA = px4[0], xB = px4[1];
  u32 zw[8] = {zA.x, zA.y, zA.z, zA.w, zB.x, zB.y, zB.z, zB.w};
  u32 xw[8] = {xA.x, xA.y, xA.z, xA.w, xB.x, xB.y, xB.z, xB.w};
  float E = 0.f, P = 1.f;
#pragma unroll
  for (int q = 0; q < 4; ++q) {
    float4 B4 = pB[q];
    float Bq[4] = {B4.x, B4.y, B4.z, B4.w};
#pragma unroll
    for (int j = 0; j < 4; ++j) {
      int k = (q << 2) + j;
      float z = (k & 1) ? hi16(zw[k >> 1]) : lo16(zw[k >> 1]);
      float xv = (k & 1) ? hi16(xw[k >> 1]) : lo16(xw[k >> 1]);
      float delta = softplusf(z + dtb);
      float a = __expf(delta * Ad);
      E = fmaf(a, E, delta * Bq[j] * xv);
      P *= a;
    }
  }
#pragma unroll
  for (int off = 1; off < 64; off <<= 1) {
    float Pp = __shfl_up(P, off);
    float Ep = __shfl_up(E, off);
    if (lane >= off) { E = fmaf(P, Ep, E); P *= Pp; }
  }
  if (lane == 63) { swp[wid] = P; swe[wid] = E; }
  __syncthreads();
  if (t < 16) {
    float p2 = swp[t], e2 = swe[t];
#pragma unroll
    for (int off = 1; off < 16; off <<= 1) {
      float pp = __shfl_up(p2, off);
      float ee = __shfl_up(e2, off);
      if (t >= off) { e2 = fmaf(p2, ee, e2); p2 *= pp; }
    }
    swp[t] = p2; swe[t] = e2;
  }
  __syncthreads();
  float hw = (wid == 0) ? 0.f : swe[wid - 1];
  float Pex = __shfl_up(P, 1);
  float Eex = __shfl_up(E, 1);
  if (lane == 0) { Pex = 1.f; Eex = 0.f; }
  float h = fmaf(Pex, hw, Eex);
  u32 ypk[8];
#pragma unroll
  for (int q = 0; q < 4; ++q) {
    float4 B4 = pB[q];
    float4 C4 = pC[q];
    float Bq[4] = {B4.x, B4.y, B4.z, B4.w};
    float Cq[4] = {C4.x, C4.y, C4.z, C4.w};
#pragma unroll
    for (int j = 0; j < 4; ++j) {
      int k = (q << 2) + j;
      float z = (k & 1) ? hi16(zw[k >> 1]) : lo16(zw[k >> 1]);
      float xv = (k & 1) ? hi16(xw[k >> 1]) : lo16(xw[k >> 1]);
      float delta = softplusf(z + dtb);
      float a = __expf(delta * Ad);
      h = fmaf(a, h, delta * Bq[j] * xv);
      u16 yb = fbf(fmaf(Dd, xv, h * Cq[j]));
      if ((k & 1) == 0) ypk[k >> 1] = yb; else ypk[k >> 1] |= (u32)yb << 16;
    }
  }
  uint4* py = (uint4*)(xy + base);
  py[0] = make_uint4(ypk[0], ypk[1], ypk[2], ypk[3]);
  py[1] = make_uint4(ypk[4], ypk[5], ypk[6], ypk[7]);
}

// ---- K7: out_proj MFMA GEMM + fused LN epilogue (f32 out, [b,o,l]) ---------
__global__ __launch_bounds__(256) void k_outproj(const u16* __restrict__ y,
                                                 const float* __restrict__ W2,
                                                 const float* __restrict__ g,
                                                 const float* __restrict__ s12,
                                                 float* __restrict__ out) {
  __shared__ __align__(16) u16 Ws[128 * 136];  // [o][c] bf16 of W2*gamma
  __shared__ __align__(16) u16 Ys[64 * 136];   // [l][c] bf16 (y^T tile)
  __shared__ float ps[4][64], pss[4][64];
  __shared__ float mean_s[64], rstd_s[64];
  int tid = threadIdx.x;
  int b = blockIdx.x >> 8;
  int l0 = (blockIdx.x & 255) << 6;
  for (int i = 0; i < 16; ++i) {
    int idx = (i << 8) + tid;
    int o = idx >> 5, c4 = (idx & 31) << 2;
    float4 w4 = *(const float4*)&W2[(o << 7) + c4];
    ushort4 s;
    s.x = fbf(w4.x * g[c4]);     s.y = fbf(w4.y * g[c4 + 1]);
    s.z = fbf(w4.z * g[c4 + 2]); s.w = fbf(w4.w * g[c4 + 3]);
    *(ushort4*)&Ws[o * 136 + c4] = s;
  }
  for (int i = 0; i < 4; ++i) {
    int idx = (i << 8) + tid;
    int c = idx >> 3, lq = (idx & 7) << 3;
    uint4 v = *(const uint4*)&y[(((long)(b << 7) + c) << 14) + l0 + lq];
    u32 vv[4] = {v.x, v.y, v.z, v.w};
#pragma unroll
    for (int r = 0; r < 8; ++r)
      Ys[(lq + r) * 136 + c] = (u16)((r & 1) ? (vv[r >> 1] >> 16) : (vv[r >> 1] & 0xffffu));
  }
  __syncthreads();
  {
    int l = tid & 63, q = tid >> 6;
    const u16* row = &Ys[l * 136 + (q << 5)];
    float s = 0.f, ss = 0.f;
#pragma unroll 8
    for (int c = 0; c < 32; ++c) { float v = bfu(row[c]); s += v; ss = fmaf(v, v, ss); }
    ps[q][l] = s; pss[q][l] = ss;
  }
  __syncthreads();
  if (tid < 64) {
    float s = ps[0][tid] + ps[1][tid] + ps[2][tid] + ps[3][tid];
    float ss = pss[0][tid] + pss[1][tid] + pss[2][tid] + pss[3][tid];
    float m = s * (1.f / 128.f);
    mean_s[tid] = m;
    rstd_s[tid] = rsqrtf(ss * (1.f / 128.f) - m * m + 1e-6f);
  }
  __syncthreads();
  int w = tid >> 6, lane = tid & 63;
  int mrow = lane & 15, quad = lane >> 4;
  f32x4 acc[2][4];
#pragma unroll
  for (int ot = 0; ot < 2; ++ot)
#pragma unroll
    for (int lt = 0; lt < 4; ++lt) acc[ot][lt] = (f32x4){0.f, 0.f, 0.f, 0.f};
#pragma unroll
  for (int kb = 0; kb < 4; ++kb) {
    int c0 = (kb << 5) + (quad << 3);
    bf16x8 af[2], bfr[4];
#pragma unroll
    for (int ot = 0; ot < 2; ++ot)
      af[ot] = ld_bf8(&Ws[((w << 5) + (ot << 4) + mrow) * 136 + c0]);
#pragma unroll
    for (int lt = 0; lt < 4; ++lt)
      bfr[lt] = ld_bf8(&Ys[((lt << 4) + mrow) * 136 + c0]);
#pragma unroll
    for (int ot = 0; ot < 2; ++ot)
#pragma unroll
      for (int lt = 0; lt < 4; ++lt)
        acc[ot][lt] = __builtin_amdgcn_mfma_f32_16x16x32_bf16(af[ot], bfr[lt], acc[ot][lt], 0, 0, 0);
  }
  float s1r[2][4], s2r[2][4];
#pragma unroll
  for (int ot = 0; ot < 2; ++ot)
#pragma unroll
    for (int r = 0; r < 4; ++r) {
      int o = (w << 5) + (ot << 4) + (quad << 2) + r;
      s1r[ot][r] = s12[o];
      s2r[ot][r] = s12[128 + o];
    }
#pragma unroll
  for (int ot = 0; ot < 2; ++ot)
#pragma unroll
    for (int lt = 0; lt < 4; ++lt) {
      int lcol = (lt << 4) + mrow;
      float mv = mean_s[lcol], rv = rstd_s[lcol];
      int obase = (w << 5) + (ot << 4) + (quad << 2);
#pragma unroll
      for (int r = 0; r < 4; ++r) {
        float v = fmaf(rv, acc[ot][lt][r] - mv * s2r[ot][r], s1r[ot][r]);
        out[(((long)(b << 7) + obase + r) << 14) + l0 + lcol] = v;
      }
    }
}

extern "C" void kernel_launch(void* const* d_in, const int* in_sizes, int n_in,
                              void* d_out, int out_size, void* d_ws, size_t ws_size,
                              hipStream_t stream) {
  const float* x         = (const float*)d_in[0];
  const float* in_proj_w = (const float*)d_in[1];
  const float* conv2d_w  = (const float*)d_in[2];
  const float* conv2d_b  = (const float*)d_in[3];
  const float* dw_w      = (const float*)d_in[4];
  const float* dw_b      = (const float*)d_in[5];
  const float* dw_ln_g   = (const float*)d_in[6];
  const float* dw_ln_b   = (const float*)d_in[7];
  const float* off_w     = (const float*)d_in[8];
  const float* off_b     = (const float*)d_in[9];
  const float* x_proj_w  = (const float*)d_in[10];
  const float* dt_w      = (const float*)d_in[11];
  const float* dt_b      = (const float*)d_in[12];
  const float* A_logs    = (const float*)d_in[13];
  const float* Ds        = (const float*)d_in[14];
  const float* out_ln_g  = (const float*)d_in[15];
  const float* out_ln_b  = (const float*)d_in[16];
  const float* out_proj_w= (const float*)d_in[17];
  float* out = (float*)d_out;

  u16* A  = (u16*)d_ws;            // xin_cl -> xs[b,c,l] -> y[b,c,l]
  u16* Bx = A + 8388608;           // xc group-blocked [b][g][y][x][c16]
  u16* Dd = Bx + 8388608;          // dts[b,c,l]
  float* Bsb   = (float*)(Dd + 8388608);
  float* Csb   = Bsb + 65536;
  float* s12   = Csb + 65536;

  hipLaunchKernelGGL(k_inproj, dim3(1025), dim3(256), 0, stream, x, in_proj_w, A,
                     out_proj_w, out_ln_g, out_ln_b, s12);
  hipLaunchKernelGGL(k_dwconv, dim3(4096), dim3(256), 0, stream, A, conv2d_w, conv2d_b, Bx);
  hipLaunchKernelGGL(k_dcnoff, dim3(1024), dim3(512), 0, stream, Bx, dw_w, dw_b,
                     dw_ln_g, dw_ln_b, off_w, off_b, x_proj_w, dt_w, A, Dd, Bsb, Csb);
  hipLaunchKernelGGL(k_scan, dim3(512), dim3(1024), 0, stream, A, Dd, Bsb, Csb, A_logs, Ds, dt_b);
  hipLaunchKernelGGL(k_outproj, dim3(1024), dim3(256), 0, stream, A, out_proj_w, out_ln_g, s12, out);
}